// Round 10
// baseline (157.483 us; speedup 1.0000x reference)
//
#include <hip/hip_runtime.h>

#define INV_I1 (1.0f/1023.0f)
#define INV_J1 (1.0f/1023.0f)

// ws layout (float offsets)
#define WS_CW     0
#define WS_RW     1024
#define WS_CH     2048
#define WS_PJT    34816
#define WS_QI     45056
#define WS_CST    55296
#define WS_LOGITS 65536
// Temporaries overlapping the logits region (dead before k_gemm):
#define WS_RHP    65536              // rowsum_h partials [1024][8][32]
#define WS_WCP    327680             // W colsum partials [16][1024]
#define WS_HPART  344064             // colsum_h partials [npart][32768]
// Xb / Wt (bf16 hi+lo planes) follow HPART at runtime.

typedef __attribute__((ext_vector_type(8))) short bf16x8;
typedef __attribute__((ext_vector_type(4))) float f32x4;

__device__ inline ushort bf16_rne(float x) {
  union { float f; unsigned u; } v; v.f = x;
  unsigned r = v.u + 0x7fffu + ((v.u >> 16) & 1u);
  return (ushort)(r >> 16);
}
__device__ inline float bf16_tof(ushort h) {
  union { unsigned u; float f; } c; c.u = ((unsigned)h) << 16;
  return c.f;
}

__device__ inline void nt_store4(float* p, float a, float b, float c, float d) {
  f32x4 v = {a, b, c, d};
  __builtin_nontemporal_store(v, (f32x4*)p);
}
__device__ inline f32x4 nt_load4(const float* p) {
  return __builtin_nontemporal_load((const f32x4*)p);
}

// ---------------------------------------------------------------------------
// Kernel 1: all independent pass-1 work in one launch (block-range roles).
// ---------------------------------------------------------------------------
__global__ __launch_bounds__(512) void k_pass1(const float* __restrict__ W,
                                               const float* __restrict__ X,
                                               const float* __restrict__ Hd,
                                               float* __restrict__ ws,
                                               float* __restrict__ hpart,
                                               float* __restrict__ wcp,
                                               ushort* __restrict__ Xb,
                                               int npart) {
  __shared__ float4 s4[512];
  int t = threadIdx.x;
  int wv = t >> 6, lane = t & 63;
  int blk = blockIdx.x;
  int nred = npart * 8;
  float* rhpart = ws + WS_RHP;

  if (blk < nred) {
    int p = blk >> 3, c = blk & 7;
    int R = 1024 / npart;
    int i0 = p * R;
    float4 ca0 = make_float4(0.f,0.f,0.f,0.f);
    float4 ca1 = make_float4(0.f,0.f,0.f,0.f);
    for (int g = 0; g < R; g += 8) {
      #pragma unroll
      for (int r = 0; r < 8; r++) {
        int i = i0 + g + r;
        const float4* rowc = (const float4*)(Hd + (size_t)i * 32768 + c * 4096);
        float4 v0 = rowc[t];
        float4 v1 = rowc[t + 512];
        ca0.x += v0.x; ca0.y += v0.y; ca0.z += v0.z; ca0.w += v0.w;
        ca1.x += v1.x; ca1.y += v1.y; ca1.z += v1.z; ca1.w += v1.w;
        float4 rs;
        rs.x = v0.x + v1.x; rs.y = v0.y + v1.y;
        rs.z = v0.z + v1.z; rs.w = v0.w + v1.w;
        #pragma unroll
        for (int off = 8; off <= 32; off <<= 1) {
          rs.x += __shfl_xor(rs.x, off, 64);
          rs.y += __shfl_xor(rs.y, off, 64);
          rs.z += __shfl_xor(rs.z, off, 64);
          rs.w += __shfl_xor(rs.w, off, 64);
        }
        if (lane < 8) s4[(r * 8 + wv) * 8 + lane] = rs;
      }
      __syncthreads();
      if (t < 64) {
        int r = t >> 3, ln = t & 7;
        float4 a = s4[(r * 8 + 0) * 8 + ln];
        #pragma unroll
        for (int w2 = 1; w2 < 8; w2++) {
          float4 b = s4[(r * 8 + w2) * 8 + ln];
          a.x += b.x; a.y += b.y; a.z += b.z; a.w += b.w;
        }
        int i = i0 + g + r;
        ((float4*)rhpart)[i * 64 + c * 8 + ln] = a;
      }
      __syncthreads();
    }
    float4* hp = (float4*)(hpart + (size_t)p * 32768 + c * 4096);
    hp[t] = ca0;
    hp[t + 512] = ca1;
  } else if (blk < nred + 128) {
    int row = (blk - nred) * 8 + wv;
    float acc = 0.f;
    #pragma unroll
    for (int m = 0; m < 16; m++) acc += W[row * 1024 + lane + 64 * m];
    #pragma unroll
    for (int off = 32; off > 0; off >>= 1) acc += __shfl_down(acc, off, 64);
    if (lane == 0) ws[WS_RW + row] = acc;
  } else if (blk < nred + 144) {
    int p2 = blk - nred - 128;
    float a0 = 0.f, a1 = 0.f;
    for (int i = p2 * 64; i < p2 * 64 + 64; i++) {
      const float* row = W + (size_t)i * 1024;
      a0 += row[t]; a1 += row[t + 512];
    }
    wcp[p2 * 1024 + t] = a0;
    wcp[p2 * 1024 + t + 512] = a1;
  } else {
    int g = (blk - nred - 144) * 512 + t;
    float4 v0 = ((const float4*)X)[g * 2];
    float4 v1 = ((const float4*)X)[g * 2 + 1];
    float xs[8] = {v0.x, v0.y, v0.z, v0.w, v1.x, v1.y, v1.z, v1.w};
    ushort hi[8], lo[8];
    #pragma unroll
    for (int e = 0; e < 8; e++) {
      hi[e] = bf16_rne(xs[e]);
      lo[e] = bf16_rne(xs[e] - bf16_tof(hi[e]));
    }
    ((uint4*)Xb)[g] = *(uint4*)hi;
    ((uint4*)(Xb + 1048576))[g] = *(uint4*)lo;
  }
}

// ---------------------------------------------------------------------------
// Kernel 2: fold colsum partials -> CH/CW + Pj; Qi; folded MLP constants
// ---------------------------------------------------------------------------
__global__ __launch_bounds__(256) void k_red2pq(const float* __restrict__ hpart,
                                                const float* __restrict__ wcp,
                                                const float* __restrict__ rhpart,
                                                const float* __restrict__ W1,
                                                const float* __restrict__ b1,
                                                const float* __restrict__ W2,
                                                const float* __restrict__ b2,
                                                const float* __restrict__ W3,
                                                const float* __restrict__ b3,
                                                float* __restrict__ ws, int npart) {
  int b = blockIdx.x, t = threadIdx.x;
  if (b < 128) {
    __shared__ float chl[256];
    __shared__ float cwl[8];
    int col = b * 256 + t;
    float acc = 0.f;
    for (int p = 0; p < npart; p++) acc += hpart[(size_t)p * 32768 + col];
    ws[WS_CH + col] = acc;
    chl[t] = acc;
    if (t < 8) {
      int j = b * 8 + t;
      float a = 0.f;
      #pragma unroll
      for (int p = 0; p < 16; p++) a += wcp[p * 1024 + j];
      ws[WS_CW + j] = a;
      cwl[t] = a;
    }
    __syncthreads();
    if (t < 80) {
      int jj = t / 10, q = t - jj * 10;
      int j = b * 8 + jj;
      float o = cwl[jj] * INV_I1 * W1[10 + q];
      for (int k = 0; k < 32; k++)
        o += chl[jj * 32 + k] * INV_I1 * W1[(35 + k) * 10 + q];
      ws[WS_PJT + q * 1024 + j] = o;
    }
  } else if (b < 132) {
    int i = (b - 128) * 256 + t;
    float rh[32];
    #pragma unroll
    for (int k = 0; k < 32; k++) rh[k] = 0.f;
    for (int c = 0; c < 8; c++) {
      #pragma unroll
      for (int k = 0; k < 32; k++) rh[k] += rhpart[i * 256 + c * 32 + k];
    }
    float sr = ws[WS_RW + i] * INV_J1;
    float out[10];
    #pragma unroll
    for (int q = 0; q < 10; q++) out[q] = b1[q] + sr * W1[20 + q];
    for (int k = 0; k < 32; k++) {
      float cc = rh[k] * INV_J1;
      #pragma unroll
      for (int q = 0; q < 10; q++) out[q] += cc * W1[(67 + k) * 10 + q];
    }
    #pragma unroll
    for (int q = 0; q < 10; q++) ws[WS_QI + i * 10 + q] = out[q];
  } else {
    for (int idx = t; idx < 330; idx += 256) {
      int r = idx / 10, q = idx - r * 10;
      float v;
      if (r == 0)
        v = W1[q] - W1[10 + q] * INV_I1 - W1[20 + q] * INV_J1;
      else
        v = W1[(2 + r) * 10 + q] - W1[(34 + r) * 10 + q] * INV_I1 - W1[(66 + r) * 10 + q] * INV_J1;
      ws[WS_CST + idx] = v;
    }
    for (int idx = t; idx < 100; idx += 256) ws[WS_CST + 330 + idx] = W2[idx];
    for (int idx = t; idx < 330; idx += 256) {
      int o = idx / 10, q2 = idx - o * 10;
      ws[WS_CST + 430 + idx] = W3[q2 * 33 + o];
    }
    if (t < 10) ws[WS_CST + 760 + t] = b2[t];
    if (t < 33) ws[WS_CST + 770 + t] = b3[t];
  }
}

// ---------------------------------------------------------------------------
// Kernel 3: per-cell MLP.
//  - Hd reads: NON-TEMPORAL (read-once; don't evict the unread Hd tail)
//  - newH writes: NON-TEMPORAL (never re-read)
//  - block order REVERSED (consume pass1's most-recently-cached rows first)
// ---------------------------------------------------------------------------
__global__ __launch_bounds__(256) void k_mlp(
    const float* __restrict__ W, const float* __restrict__ Hd,
    const float* __restrict__ ws,
    float* __restrict__ newW, float* __restrict__ newH) {
  __shared__ __align__(16) float hbuf[8192];
  int t = threadIdx.x;
  int blk = 4095 - (int)blockIdx.x;   // reversed traversal
  int cell0 = blk * 256;
  int i = blk >> 2;
  int j0 = (blk & 3) * 256;
  const float* cst = ws + WS_CST;

  const float* srcf = Hd + (size_t)cell0 * 32;
  #pragma unroll
  for (int m = 0; m < 8; m++) {
    int s = t + 256 * m;
    f32x4 v = nt_load4(srcf + s * 4);
    int cs = s >> 3, ms = s & 7;
    int slot = cs * 8 + ((ms + cs) & 7);
    *(f32x4*)&hbuf[slot * 4] = v;
  }
  float w0 = W[cell0 + t];
  float pj[10];
  #pragma unroll
  for (int q = 0; q < 10; q++) pj[q] = ws[WS_PJT + q * 1024 + j0 + t];
  float qv[10];
  #pragma unroll
  for (int q = 0; q < 10; q++) qv[q] = ws[WS_QI + i * 10 + q];
  __syncthreads();

  float h[32];
  #pragma unroll
  for (int m = 0; m < 8; m++) {
    int slot = t * 8 + ((m + t) & 7);
    float4 v = *(const float4*)&hbuf[slot * 4];
    h[m * 4 + 0] = v.x; h[m * 4 + 1] = v.y; h[m * 4 + 2] = v.z; h[m * 4 + 3] = v.w;
  }

  float z[10];
  #pragma unroll
  for (int q = 0; q < 10; q++) z[q] = pj[q] + qv[q] + w0 * cst[q];
  #pragma unroll
  for (int k = 0; k < 32; k++) {
    #pragma unroll
    for (int q = 0; q < 10; q++) z[q] += h[k] * cst[(k + 1) * 10 + q];
  }
  #pragma unroll
  for (int q = 0; q < 10; q++) z[q] = fmaxf(z[q], 0.f);

  float y[10];
  #pragma unroll
  for (int q2 = 0; q2 < 10; q2++) y[q2] = cst[760 + q2];
  #pragma unroll
  for (int q = 0; q < 10; q++) {
    #pragma unroll
    for (int q2 = 0; q2 < 10; q2++) y[q2] += z[q] * cst[330 + q * 10 + q2];
  }
  #pragma unroll
  for (int q2 = 0; q2 < 10; q2++) y[q2] = fmaxf(y[q2], 0.f);

  float u = cst[770];
  #pragma unroll
  for (int q2 = 0; q2 < 10; q2++) u += y[q2] * cst[430 + q2];
  newW[cell0 + t] = w0 + u;

  #pragma unroll
  for (int o = 1; o < 33; o++) {
    float a = cst[770 + o];
    #pragma unroll
    for (int q2 = 0; q2 < 10; q2++) a += y[q2] * cst[430 + o * 10 + q2];
    h[o - 1] += a;
  }

  #pragma unroll
  for (int m = 0; m < 8; m++) {
    int slot = t * 8 + ((m + t) & 7);
    *(float4*)&hbuf[slot * 4] = make_float4(h[m * 4], h[m * 4 + 1], h[m * 4 + 2], h[m * 4 + 3]);
  }
  __syncthreads();
  float* dstf = newH + (size_t)cell0 * 32;
  #pragma unroll
  for (int m = 0; m < 8; m++) {
    int s = t + 256 * m;
    int cs = s >> 3, ms = s & 7;
    int slot = cs * 8 + ((ms + cs) & 7);
    const float* hv = &hbuf[slot * 4];
    nt_store4(dstf + s * 4, hv[0], hv[1], hv[2], hv[3]);
  }
}

// ---------------------------------------------------------------------------
// Kernel 4: transpose+split newW (f32 [k][n]) -> Wt bf16 hi/lo [n][k]
// ---------------------------------------------------------------------------
__global__ __launch_bounds__(256) void k_wt(const float* __restrict__ nW,
                                            ushort* __restrict__ Wt) {
  __shared__ float buf[64][65];
  int t = threadIdx.x;
  int i0 = blockIdx.y * 64, j0 = blockIdx.x * 64;
  int jl = t & 63, rr = t >> 6;
  #pragma unroll
  for (int r2 = 0; r2 < 16; r2++) {
    int il = r2 * 4 + rr;
    buf[jl][il] = nW[(size_t)(i0 + il) * 1024 + j0 + jl];
  }
  __syncthreads();
  int jw = t >> 2, iq = (t & 3) * 16;
  ushort hi[16], lo[16];
  #pragma unroll
  for (int e = 0; e < 16; e++) {
    float x = buf[jw][iq + e];
    ushort h = bf16_rne(x);
    hi[e] = h;
    lo[e] = bf16_rne(x - bf16_tof(h));
  }
  size_t base = (size_t)(j0 + jw) * 1024 + i0 + iq;
  *(uint4*)(Wt + base)     = *(uint4*)hi;
  *(uint4*)(Wt + base + 8) = *(uint4*)(hi + 8);
  *(uint4*)(Wt + 1048576 + base)     = *(uint4*)lo;
  *(uint4*)(Wt + 1048576 + base + 8) = *(uint4*)(lo + 8);
}

// ---------------------------------------------------------------------------
// Kernel 5: MFMA GEMM (256 blocks, 64x64 tile, 3-term bf16 split)
// ---------------------------------------------------------------------------
__global__ __launch_bounds__(256) void k_gemm(const ushort* __restrict__ Xb,
                                              const ushort* __restrict__ Wt,
                                              float* __restrict__ C) {
  int t = threadIdx.x;
  int w = t >> 6, l = t & 63;
  int m0 = blockIdx.y * 64 + (w >> 1) * 32;
  int n0 = blockIdx.x * 64 + (w & 1) * 32;
  int lr = l & 15;
  int kg = (l >> 4) * 8;
  const ushort* Xhi = Xb;
  const ushort* Xlo = Xb + 1048576;
  const ushort* Whi = Wt;
  const ushort* Wlo = Wt + 1048576;
  const size_t ra0 = (size_t)(m0 + lr) * 1024;
  const size_t ra1 = (size_t)(m0 + 16 + lr) * 1024;
  const size_t cb0 = (size_t)(n0 + lr) * 1024;
  const size_t cb1 = (size_t)(n0 + 16 + lr) * 1024;
  f32x4 acc00 = {0.f, 0.f, 0.f, 0.f};
  f32x4 acc01 = {0.f, 0.f, 0.f, 0.f};
  f32x4 acc10 = {0.f, 0.f, 0.f, 0.f};
  f32x4 acc11 = {0.f, 0.f, 0.f, 0.f};
  #pragma unroll 2
  for (int k0 = 0; k0 < 1024; k0 += 32) {
    int o = k0 + kg;
    bf16x8 ah0 = *(const bf16x8*)(Xhi + ra0 + o);
    bf16x8 ah1 = *(const bf16x8*)(Xhi + ra1 + o);
    bf16x8 al0 = *(const bf16x8*)(Xlo + ra0 + o);
    bf16x8 al1 = *(const bf16x8*)(Xlo + ra1 + o);
    bf16x8 bh0 = *(const bf16x8*)(Whi + cb0 + o);
    bf16x8 bh1 = *(const bf16x8*)(Whi + cb1 + o);
    bf16x8 bl0 = *(const bf16x8*)(Wlo + cb0 + o);
    bf16x8 bl1 = *(const bf16x8*)(Wlo + cb1 + o);
    acc00 = __builtin_amdgcn_mfma_f32_16x16x32_bf16(ah0, bh0, acc00, 0, 0, 0);
    acc01 = __builtin_amdgcn_mfma_f32_16x16x32_bf16(ah0, bh1, acc01, 0, 0, 0);
    acc10 = __builtin_amdgcn_mfma_f32_16x16x32_bf16(ah1, bh0, acc10, 0, 0, 0);
    acc11 = __builtin_amdgcn_mfma_f32_16x16x32_bf16(ah1, bh1, acc11, 0, 0, 0);
    acc00 = __builtin_amdgcn_mfma_f32_16x16x32_bf16(ah0, bl0, acc00, 0, 0, 0);
    acc01 = __builtin_amdgcn_mfma_f32_16x16x32_bf16(ah0, bl1, acc01, 0, 0, 0);
    acc10 = __builtin_amdgcn_mfma_f32_16x16x32_bf16(ah1, bl0, acc10, 0, 0, 0);
    acc11 = __builtin_amdgcn_mfma_f32_16x16x32_bf16(ah1, bl1, acc11, 0, 0, 0);
    acc00 = __builtin_amdgcn_mfma_f32_16x16x32_bf16(al0, bh0, acc00, 0, 0, 0);
    acc01 = __builtin_amdgcn_mfma_f32_16x16x32_bf16(al0, bh1, acc01, 0, 0, 0);
    acc10 = __builtin_amdgcn_mfma_f32_16x16x32_bf16(al1, bh0, acc10, 0, 0, 0);
    acc11 = __builtin_amdgcn_mfma_f32_16x16x32_bf16(al1, bh1, acc11, 0, 0, 0);
  }
  int rbase = m0 + (l >> 4) * 4;
  #pragma unroll
  for (int r = 0; r < 4; r++) {
    C[(size_t)(rbase + r) * 1024 + n0 + lr]           = acc00[r];
    C[(size_t)(rbase + r) * 1024 + n0 + 16 + lr]      = acc01[r];
    C[(size_t)(rbase + 16 + r) * 1024 + n0 + lr]      = acc10[r];
    C[(size_t)(rbase + 16 + r) * 1024 + n0 + 16 + lr] = acc11[r];
  }
}

// ---------------------------------------------------------------------------
// Kernel 6: row softmax (nt stores for probs)
// ---------------------------------------------------------------------------
__global__ __launch_bounds__(256) void k_softmax(const float* __restrict__ L,
                                                 float* __restrict__ P) {
  __shared__ float sm[4], ss[4];
  int r = blockIdx.x, t = threadIdx.x;
  const float* row = L + r * 1024;
  float v0 = row[t], v1 = row[t + 256], v2 = row[t + 512], v3 = row[t + 768];
  float m = fmaxf(fmaxf(v0, v1), fmaxf(v2, v3));
  #pragma unroll
  for (int off = 32; off > 0; off >>= 1) m = fmaxf(m, __shfl_xor(m, off, 64));
  int wv = t >> 6, lane = t & 63;
  if (lane == 0) sm[wv] = m;
  __syncthreads();
  m = fmaxf(fmaxf(sm[0], sm[1]), fmaxf(sm[2], sm[3]));
  float e0 = expf(v0 - m), e1 = expf(v1 - m), e2 = expf(v2 - m), e3 = expf(v3 - m);
  float s = e0 + e1 + e2 + e3;
  #pragma unroll
  for (int off = 32; off > 0; off >>= 1) s += __shfl_xor(s, off, 64);
  if (lane == 0) ss[wv] = s;
  __syncthreads();
  s = ss[0] + ss[1] + ss[2] + ss[3];
  float inv = 1.0f / s;
  float* prow = P + r * 1024;
  __builtin_nontemporal_store(e0 * inv, &prow[t]);
  __builtin_nontemporal_store(e1 * inv, &prow[t + 256]);
  __builtin_nontemporal_store(e2 * inv, &prow[t + 512]);
  __builtin_nontemporal_store(e3 * inv, &prow[t + 768]);
}

extern "C" void kernel_launch(void* const* d_in, const int* in_sizes, int n_in,
                              void* d_out, int out_size, void* d_ws, size_t ws_size,
                              hipStream_t stream) {
  const float* X  = (const float*)d_in[0];
  const float* W  = (const float*)d_in[1];
  const float* Hd = (const float*)d_in[2];
  const float* W1 = (const float*)d_in[3];
  const float* b1 = (const float*)d_in[4];
  const float* W2 = (const float*)d_in[5];
  const float* b2 = (const float*)d_in[6];
  const float* W3 = (const float*)d_in[7];
  const float* b3 = (const float*)d_in[8];
  float* out   = (float*)d_out;
  float* probs = out;
  float* newW  = out + 1048576;
  float* newH  = out + 2097152;
  float* ws = (float*)d_ws;

  size_t wsf = ws_size / 4;
  int npart = 64;
  while (npart > 8 &&
         (size_t)WS_HPART + (size_t)npart * 32768ull + 2097152ull > wsf)
    npart >>= 1;
  float*  rhpart = ws + WS_RHP;
  float*  wcp    = ws + WS_WCP;
  float*  hpart  = ws + WS_HPART;
  size_t  xb0    = (size_t)WS_HPART + (size_t)npart * 32768ull;
  ushort* Xb     = (ushort*)(ws + xb0);
  ushort* Wt     = (ushort*)(ws + xb0 + 1048576);

  k_pass1<<<npart * 8 + 400, 512, 0, stream>>>(W, X, Hd, ws, hpart, wcp, Xb,
                                               npart);
  k_red2pq<<<133, 256, 0, stream>>>(hpart, wcp, rhpart, W1, b1, W2, b2, W3, b3,
                                    ws, npart);
  k_mlp<<<4096, 256, 0, stream>>>(W, Hd, ws, newW, newH);
  k_wt<<<dim3(16, 16), 256, 0, stream>>>(newW, Wt);
  k_gemm<<<dim3(16, 16), 256, 0, stream>>>(Xb, Wt, ws + WS_LOGITS);
  k_softmax<<<1024, 256, 0, stream>>>(ws + WS_LOGITS, probs);
}

// Round 11
// 152.458 us; speedup vs baseline: 1.0330x; 1.0330x over previous
//
#include <hip/hip_runtime.h>

#define INV_I1 (1.0f/1023.0f)
#define INV_J1 (1.0f/1023.0f)

// ws layout (float offsets)
#define WS_CW     0
#define WS_RW     1024
#define WS_CH     2048
#define WS_PJT    34816
#define WS_QI     45056
#define WS_CST    55296
#define WS_LOGITS 65536
// Temporaries overlapping the logits region (dead before k_gemm):
#define WS_RHP    65536              // rowsum_h partials [1024][8][32]
#define WS_WCP    327680             // W colsum partials [16][1024]
#define WS_HPART  344064             // colsum_h partials [npart][32768]
// Xb / Wt (bf16 hi+lo planes) follow HPART at runtime.

typedef __attribute__((ext_vector_type(8))) short bf16x8;
typedef __attribute__((ext_vector_type(4))) float f32x4;

__device__ inline ushort bf16_rne(float x) {
  union { float f; unsigned u; } v; v.f = x;
  unsigned r = v.u + 0x7fffu + ((v.u >> 16) & 1u);
  return (ushort)(r >> 16);
}
__device__ inline float bf16_tof(ushort h) {
  union { unsigned u; float f; } c; c.u = ((unsigned)h) << 16;
  return c.f;
}

__device__ inline void nt_store4(float* p, float a, float b, float c, float d) {
  f32x4 v = {a, b, c, d};
  __builtin_nontemporal_store(v, (f32x4*)p);
}

// ---------------------------------------------------------------------------
// Kernel 1: all independent pass-1 work in one launch (block-range roles).
// ---------------------------------------------------------------------------
__global__ __launch_bounds__(512) void k_pass1(const float* __restrict__ W,
                                               const float* __restrict__ X,
                                               const float* __restrict__ Hd,
                                               float* __restrict__ ws,
                                               float* __restrict__ hpart,
                                               float* __restrict__ wcp,
                                               ushort* __restrict__ Xb,
                                               int npart) {
  __shared__ float4 s4[512];
  int t = threadIdx.x;
  int wv = t >> 6, lane = t & 63;
  int blk = blockIdx.x;
  int nred = npart * 8;
  float* rhpart = ws + WS_RHP;

  if (blk < nred) {
    int p = blk >> 3, c = blk & 7;
    int R = 1024 / npart;
    int i0 = p * R;
    float4 ca0 = make_float4(0.f,0.f,0.f,0.f);
    float4 ca1 = make_float4(0.f,0.f,0.f,0.f);
    for (int g = 0; g < R; g += 8) {
      #pragma unroll
      for (int r = 0; r < 8; r++) {
        int i = i0 + g + r;
        const float4* rowc = (const float4*)(Hd + (size_t)i * 32768 + c * 4096);
        float4 v0 = rowc[t];
        float4 v1 = rowc[t + 512];
        ca0.x += v0.x; ca0.y += v0.y; ca0.z += v0.z; ca0.w += v0.w;
        ca1.x += v1.x; ca1.y += v1.y; ca1.z += v1.z; ca1.w += v1.w;
        float4 rs;
        rs.x = v0.x + v1.x; rs.y = v0.y + v1.y;
        rs.z = v0.z + v1.z; rs.w = v0.w + v1.w;
        #pragma unroll
        for (int off = 8; off <= 32; off <<= 1) {
          rs.x += __shfl_xor(rs.x, off, 64);
          rs.y += __shfl_xor(rs.y, off, 64);
          rs.z += __shfl_xor(rs.z, off, 64);
          rs.w += __shfl_xor(rs.w, off, 64);
        }
        if (lane < 8) s4[(r * 8 + wv) * 8 + lane] = rs;
      }
      __syncthreads();
      if (t < 64) {
        int r = t >> 3, ln = t & 7;
        float4 a = s4[(r * 8 + 0) * 8 + ln];
        #pragma unroll
        for (int w2 = 1; w2 < 8; w2++) {
          float4 b = s4[(r * 8 + w2) * 8 + ln];
          a.x += b.x; a.y += b.y; a.z += b.z; a.w += b.w;
        }
        int i = i0 + g + r;
        ((float4*)rhpart)[i * 64 + c * 8 + ln] = a;
      }
      __syncthreads();
    }
    float4* hp = (float4*)(hpart + (size_t)p * 32768 + c * 4096);
    hp[t] = ca0;
    hp[t + 512] = ca1;
  } else if (blk < nred + 128) {
    int row = (blk - nred) * 8 + wv;
    float acc = 0.f;
    #pragma unroll
    for (int m = 0; m < 16; m++) acc += W[row * 1024 + lane + 64 * m];
    #pragma unroll
    for (int off = 32; off > 0; off >>= 1) acc += __shfl_down(acc, off, 64);
    if (lane == 0) ws[WS_RW + row] = acc;
  } else if (blk < nred + 144) {
    int p2 = blk - nred - 128;
    float a0 = 0.f, a1 = 0.f;
    for (int i = p2 * 64; i < p2 * 64 + 64; i++) {
      const float* row = W + (size_t)i * 1024;
      a0 += row[t]; a1 += row[t + 512];
    }
    wcp[p2 * 1024 + t] = a0;
    wcp[p2 * 1024 + t + 512] = a1;
  } else {
    int g = (blk - nred - 144) * 512 + t;
    float4 v0 = ((const float4*)X)[g * 2];
    float4 v1 = ((const float4*)X)[g * 2 + 1];
    float xs[8] = {v0.x, v0.y, v0.z, v0.w, v1.x, v1.y, v1.z, v1.w};
    ushort hi[8], lo[8];
    #pragma unroll
    for (int e = 0; e < 8; e++) {
      hi[e] = bf16_rne(xs[e]);
      lo[e] = bf16_rne(xs[e] - bf16_tof(hi[e]));
    }
    ((uint4*)Xb)[g] = *(uint4*)hi;
    ((uint4*)(Xb + 1048576))[g] = *(uint4*)lo;
  }
}

// ---------------------------------------------------------------------------
// Kernel 2: fold colsum partials -> CH/CW + Pj; Qi; folded MLP constants
// ---------------------------------------------------------------------------
__global__ __launch_bounds__(256) void k_red2pq(const float* __restrict__ hpart,
                                                const float* __restrict__ wcp,
                                                const float* __restrict__ rhpart,
                                                const float* __restrict__ W1,
                                                const float* __restrict__ b1,
                                                const float* __restrict__ W2,
                                                const float* __restrict__ b2,
                                                const float* __restrict__ W3,
                                                const float* __restrict__ b3,
                                                float* __restrict__ ws, int npart) {
  int b = blockIdx.x, t = threadIdx.x;
  if (b < 128) {
    __shared__ float chl[256];
    __shared__ float cwl[8];
    int col = b * 256 + t;
    float acc = 0.f;
    for (int p = 0; p < npart; p++) acc += hpart[(size_t)p * 32768 + col];
    ws[WS_CH + col] = acc;
    chl[t] = acc;
    if (t < 8) {
      int j = b * 8 + t;
      float a = 0.f;
      #pragma unroll
      for (int p = 0; p < 16; p++) a += wcp[p * 1024 + j];
      ws[WS_CW + j] = a;
      cwl[t] = a;
    }
    __syncthreads();
    if (t < 80) {
      int jj = t / 10, q = t - jj * 10;
      int j = b * 8 + jj;
      float o = cwl[jj] * INV_I1 * W1[10 + q];
      for (int k = 0; k < 32; k++)
        o += chl[jj * 32 + k] * INV_I1 * W1[(35 + k) * 10 + q];
      ws[WS_PJT + q * 1024 + j] = o;
    }
  } else if (b < 132) {
    int i = (b - 128) * 256 + t;
    float rh[32];
    #pragma unroll
    for (int k = 0; k < 32; k++) rh[k] = 0.f;
    for (int c = 0; c < 8; c++) {
      #pragma unroll
      for (int k = 0; k < 32; k++) rh[k] += rhpart[i * 256 + c * 32 + k];
    }
    float sr = ws[WS_RW + i] * INV_J1;
    float out[10];
    #pragma unroll
    for (int q = 0; q < 10; q++) out[q] = b1[q] + sr * W1[20 + q];
    for (int k = 0; k < 32; k++) {
      float cc = rh[k] * INV_J1;
      #pragma unroll
      for (int q = 0; q < 10; q++) out[q] += cc * W1[(67 + k) * 10 + q];
    }
    #pragma unroll
    for (int q = 0; q < 10; q++) ws[WS_QI + i * 10 + q] = out[q];
  } else {
    for (int idx = t; idx < 330; idx += 256) {
      int r = idx / 10, q = idx - r * 10;
      float v;
      if (r == 0)
        v = W1[q] - W1[10 + q] * INV_I1 - W1[20 + q] * INV_J1;
      else
        v = W1[(2 + r) * 10 + q] - W1[(34 + r) * 10 + q] * INV_I1 - W1[(66 + r) * 10 + q] * INV_J1;
      ws[WS_CST + idx] = v;
    }
    for (int idx = t; idx < 100; idx += 256) ws[WS_CST + 330 + idx] = W2[idx];
    for (int idx = t; idx < 330; idx += 256) {
      int o = idx / 10, q2 = idx - o * 10;
      ws[WS_CST + 430 + idx] = W3[q2 * 33 + o];
    }
    if (t < 10) ws[WS_CST + 760 + t] = b2[t];
    if (t < 33) ws[WS_CST + 770 + t] = b3[t];
  }
}

// ---------------------------------------------------------------------------
// Kernel 3: per-cell MLP (round-9 winning config: normal loads, natural block
// order, NON-TEMPORAL newH stores).
// ---------------------------------------------------------------------------
__global__ __launch_bounds__(256) void k_mlp(
    const float* __restrict__ W, const float* __restrict__ Hd,
    const float* __restrict__ ws,
    float* __restrict__ newW, float* __restrict__ newH) {
  __shared__ __align__(16) float hbuf[8192];
  int t = threadIdx.x;
  int cell0 = blockIdx.x * 256;
  int i = blockIdx.x >> 2;
  int j0 = (blockIdx.x & 3) * 256;
  const float* cst = ws + WS_CST;

  const float4* src = (const float4*)(Hd + (size_t)cell0 * 32);
  #pragma unroll
  for (int m = 0; m < 8; m++) {
    int s = t + 256 * m;
    float4 v = src[s];
    int cs = s >> 3, ms = s & 7;
    int slot = cs * 8 + ((ms + cs) & 7);
    *(float4*)&hbuf[slot * 4] = v;
  }
  float w0 = W[cell0 + t];
  float pj[10];
  #pragma unroll
  for (int q = 0; q < 10; q++) pj[q] = ws[WS_PJT + q * 1024 + j0 + t];
  float qv[10];
  #pragma unroll
  for (int q = 0; q < 10; q++) qv[q] = ws[WS_QI + i * 10 + q];
  __syncthreads();

  float h[32];
  #pragma unroll
  for (int m = 0; m < 8; m++) {
    int slot = t * 8 + ((m + t) & 7);
    float4 v = *(const float4*)&hbuf[slot * 4];
    h[m * 4 + 0] = v.x; h[m * 4 + 1] = v.y; h[m * 4 + 2] = v.z; h[m * 4 + 3] = v.w;
  }

  float z[10];
  #pragma unroll
  for (int q = 0; q < 10; q++) z[q] = pj[q] + qv[q] + w0 * cst[q];
  #pragma unroll
  for (int k = 0; k < 32; k++) {
    #pragma unroll
    for (int q = 0; q < 10; q++) z[q] += h[k] * cst[(k + 1) * 10 + q];
  }
  #pragma unroll
  for (int q = 0; q < 10; q++) z[q] = fmaxf(z[q], 0.f);

  float y[10];
  #pragma unroll
  for (int q2 = 0; q2 < 10; q2++) y[q2] = cst[760 + q2];
  #pragma unroll
  for (int q = 0; q < 10; q++) {
    #pragma unroll
    for (int q2 = 0; q2 < 10; q2++) y[q2] += z[q] * cst[330 + q * 10 + q2];
  }
  #pragma unroll
  for (int q2 = 0; q2 < 10; q2++) y[q2] = fmaxf(y[q2], 0.f);

  float u = cst[770];
  #pragma unroll
  for (int q2 = 0; q2 < 10; q2++) u += y[q2] * cst[430 + q2];
  newW[cell0 + t] = w0 + u;

  #pragma unroll
  for (int o = 1; o < 33; o++) {
    float a = cst[770 + o];
    #pragma unroll
    for (int q2 = 0; q2 < 10; q2++) a += y[q2] * cst[430 + o * 10 + q2];
    h[o - 1] += a;
  }

  #pragma unroll
  for (int m = 0; m < 8; m++) {
    int slot = t * 8 + ((m + t) & 7);
    *(float4*)&hbuf[slot * 4] = make_float4(h[m * 4], h[m * 4 + 1], h[m * 4 + 2], h[m * 4 + 3]);
  }
  __syncthreads();
  float* dstf = newH + (size_t)cell0 * 32;
  #pragma unroll
  for (int m = 0; m < 8; m++) {
    int s = t + 256 * m;
    int cs = s >> 3, ms = s & 7;
    int slot = cs * 8 + ((ms + cs) & 7);
    const float* hv = &hbuf[slot * 4];
    nt_store4(dstf + s * 4, hv[0], hv[1], hv[2], hv[3]);
  }
}

// ---------------------------------------------------------------------------
// Kernel 4: transpose+split newW (f32 [k][n]) -> Wt bf16 hi/lo [n][k]
// ---------------------------------------------------------------------------
__global__ __launch_bounds__(256) void k_wt(const float* __restrict__ nW,
                                            ushort* __restrict__ Wt) {
  __shared__ float buf[64][65];
  int t = threadIdx.x;
  int i0 = blockIdx.y * 64, j0 = blockIdx.x * 64;
  int jl = t & 63, rr = t >> 6;
  #pragma unroll
  for (int r2 = 0; r2 < 16; r2++) {
    int il = r2 * 4 + rr;
    buf[jl][il] = nW[(size_t)(i0 + il) * 1024 + j0 + jl];
  }
  __syncthreads();
  int jw = t >> 2, iq = (t & 3) * 16;
  ushort hi[16], lo[16];
  #pragma unroll
  for (int e = 0; e < 16; e++) {
    float x = buf[jw][iq + e];
    ushort h = bf16_rne(x);
    hi[e] = h;
    lo[e] = bf16_rne(x - bf16_tof(h));
  }
  size_t base = (size_t)(j0 + jw) * 1024 + i0 + iq;
  *(uint4*)(Wt + base)     = *(uint4*)hi;
  *(uint4*)(Wt + base + 8) = *(uint4*)(hi + 8);
  *(uint4*)(Wt + 1048576 + base)     = *(uint4*)lo;
  *(uint4*)(Wt + 1048576 + base + 8) = *(uint4*)(lo + 8);
}

// ---------------------------------------------------------------------------
// Kernel 5: MFMA GEMM (256 blocks, 64x64 tile, 3-term bf16 split)
// ---------------------------------------------------------------------------
__global__ __launch_bounds__(256) void k_gemm(const ushort* __restrict__ Xb,
                                              const ushort* __restrict__ Wt,
                                              float* __restrict__ C) {
  int t = threadIdx.x;
  int w = t >> 6, l = t & 63;
  int m0 = blockIdx.y * 64 + (w >> 1) * 32;
  int n0 = blockIdx.x * 64 + (w & 1) * 32;
  int lr = l & 15;
  int kg = (l >> 4) * 8;
  const ushort* Xhi = Xb;
  const ushort* Xlo = Xb + 1048576;
  const ushort* Whi = Wt;
  const ushort* Wlo = Wt + 1048576;
  const size_t ra0 = (size_t)(m0 + lr) * 1024;
  const size_t ra1 = (size_t)(m0 + 16 + lr) * 1024;
  const size_t cb0 = (size_t)(n0 + lr) * 1024;
  const size_t cb1 = (size_t)(n0 + 16 + lr) * 1024;
  f32x4 acc00 = {0.f, 0.f, 0.f, 0.f};
  f32x4 acc01 = {0.f, 0.f, 0.f, 0.f};
  f32x4 acc10 = {0.f, 0.f, 0.f, 0.f};
  f32x4 acc11 = {0.f, 0.f, 0.f, 0.f};
  #pragma unroll 2
  for (int k0 = 0; k0 < 1024; k0 += 32) {
    int o = k0 + kg;
    bf16x8 ah0 = *(const bf16x8*)(Xhi + ra0 + o);
    bf16x8 ah1 = *(const bf16x8*)(Xhi + ra1 + o);
    bf16x8 al0 = *(const bf16x8*)(Xlo + ra0 + o);
    bf16x8 al1 = *(const bf16x8*)(Xlo + ra1 + o);
    bf16x8 bh0 = *(const bf16x8*)(Whi + cb0 + o);
    bf16x8 bh1 = *(const bf16x8*)(Whi + cb1 + o);
    bf16x8 bl0 = *(const bf16x8*)(Wlo + cb0 + o);
    bf16x8 bl1 = *(const bf16x8*)(Wlo + cb1 + o);
    acc00 = __builtin_amdgcn_mfma_f32_16x16x32_bf16(ah0, bh0, acc00, 0, 0, 0);
    acc01 = __builtin_amdgcn_mfma_f32_16x16x32_bf16(ah0, bh1, acc01, 0, 0, 0);
    acc10 = __builtin_amdgcn_mfma_f32_16x16x32_bf16(ah1, bh0, acc10, 0, 0, 0);
    acc11 = __builtin_amdgcn_mfma_f32_16x16x32_bf16(ah1, bh1, acc11, 0, 0, 0);
    acc00 = __builtin_amdgcn_mfma_f32_16x16x32_bf16(ah0, bl0, acc00, 0, 0, 0);
    acc01 = __builtin_amdgcn_mfma_f32_16x16x32_bf16(ah0, bl1, acc01, 0, 0, 0);
    acc10 = __builtin_amdgcn_mfma_f32_16x16x32_bf16(ah1, bl0, acc10, 0, 0, 0);
    acc11 = __builtin_amdgcn_mfma_f32_16x16x32_bf16(ah1, bl1, acc11, 0, 0, 0);
    acc00 = __builtin_amdgcn_mfma_f32_16x16x32_bf16(al0, bh0, acc00, 0, 0, 0);
    acc01 = __builtin_amdgcn_mfma_f32_16x16x32_bf16(al0, bh1, acc01, 0, 0, 0);
    acc10 = __builtin_amdgcn_mfma_f32_16x16x32_bf16(al1, bh0, acc10, 0, 0, 0);
    acc11 = __builtin_amdgcn_mfma_f32_16x16x32_bf16(al1, bh1, acc11, 0, 0, 0);
  }
  int rbase = m0 + (l >> 4) * 4;
  #pragma unroll
  for (int r = 0; r < 4; r++) {
    C[(size_t)(rbase + r) * 1024 + n0 + lr]           = acc00[r];
    C[(size_t)(rbase + r) * 1024 + n0 + 16 + lr]      = acc01[r];
    C[(size_t)(rbase + 16 + r) * 1024 + n0 + lr]      = acc10[r];
    C[(size_t)(rbase + 16 + r) * 1024 + n0 + 16 + lr] = acc11[r];
  }
}

// ---------------------------------------------------------------------------
// Kernel 6: row softmax (nt stores for probs)
// ---------------------------------------------------------------------------
__global__ __launch_bounds__(256) void k_softmax(const float* __restrict__ L,
                                                 float* __restrict__ P) {
  __shared__ float sm[4], ss[4];
  int r = blockIdx.x, t = threadIdx.x;
  const float* row = L + r * 1024;
  float v0 = row[t], v1 = row[t + 256], v2 = row[t + 512], v3 = row[t + 768];
  float m = fmaxf(fmaxf(v0, v1), fmaxf(v2, v3));
  #pragma unroll
  for (int off = 32; off > 0; off >>= 1) m = fmaxf(m, __shfl_xor(m, off, 64));
  int wv = t >> 6, lane = t & 63;
  if (lane == 0) sm[wv] = m;
  __syncthreads();
  m = fmaxf(fmaxf(sm[0], sm[1]), fmaxf(sm[2], sm[3]));
  float e0 = expf(v0 - m), e1 = expf(v1 - m), e2 = expf(v2 - m), e3 = expf(v3 - m);
  float s = e0 + e1 + e2 + e3;
  #pragma unroll
  for (int off = 32; off > 0; off >>= 1) s += __shfl_xor(s, off, 64);
  if (lane == 0) ss[wv] = s;
  __syncthreads();
  s = ss[0] + ss[1] + ss[2] + ss[3];
  float inv = 1.0f / s;
  float* prow = P + r * 1024;
  __builtin_nontemporal_store(e0 * inv, &prow[t]);
  __builtin_nontemporal_store(e1 * inv, &prow[t + 256]);
  __builtin_nontemporal_store(e2 * inv, &prow[t + 512]);
  __builtin_nontemporal_store(e3 * inv, &prow[t + 768]);
}

extern "C" void kernel_launch(void* const* d_in, const int* in_sizes, int n_in,
                              void* d_out, int out_size, void* d_ws, size_t ws_size,
                              hipStream_t stream) {
  const float* X  = (const float*)d_in[0];
  const float* W  = (const float*)d_in[1];
  const float* Hd = (const float*)d_in[2];
  const float* W1 = (const float*)d_in[3];
  const float* b1 = (const float*)d_in[4];
  const float* W2 = (const float*)d_in[5];
  const float* b2 = (const float*)d_in[6];
  const float* W3 = (const float*)d_in[7];
  const float* b3 = (const float*)d_in[8];
  float* out   = (float*)d_out;
  float* probs = out;
  float* newW  = out + 1048576;
  float* newH  = out + 2097152;
  float* ws = (float*)d_ws;

  size_t wsf = ws_size / 4;
  int npart = 64;
  while (npart > 8 &&
         (size_t)WS_HPART + (size_t)npart * 32768ull + 2097152ull > wsf)
    npart >>= 1;
  float*  rhpart = ws + WS_RHP;
  float*  wcp    = ws + WS_WCP;
  float*  hpart  = ws + WS_HPART;
  size_t  xb0    = (size_t)WS_HPART + (size_t)npart * 32768ull;
  ushort* Xb     = (ushort*)(ws + xb0);
  ushort* Wt     = (ushort*)(ws + xb0 + 1048576);

  k_pass1<<<npart * 8 + 400, 512, 0, stream>>>(W, X, Hd, ws, hpart, wcp, Xb,
                                               npart);
  k_red2pq<<<133, 256, 0, stream>>>(hpart, wcp, rhpart, W1, b1, W2, b2, W3, b3,
                                    ws, npart);
  k_mlp<<<4096, 256, 0, stream>>>(W, Hd, ws, newW, newH);
  k_wt<<<dim3(16, 16), 256, 0, stream>>>(newW, Wt);
  k_gemm<<<dim3(16, 16), 256, 0, stream>>>(Xb, Wt, ws + WS_LOGITS);
  k_softmax<<<1024, 256, 0, stream>>>(ws + WS_LOGITS, probs);
}